// Round 7
// baseline (1312.954 us; speedup 1.0000x reference)
//
#include <hip/hip_runtime.h>
#include <cstddef>

#define B_     512
#define IN_    1023
#define INP1   1024
#define OUT_   512
#define OUT4   128
#define CLIPV  2.0f
#define LNEPS  1e-5f

// fused spin-sync geometry
#define STRIPS 16        // strips per sample
#define ROWS   64        // rows per strip
#define FT     512       // threads per block
#define KPT    16        // rows per thread (ROWS / (FT/128))

typedef float fx4 __attribute__((ext_vector_type(4)));

__device__ __forceinline__ float2 block_reduce2(float a, float b, float2* lds) {
    #pragma unroll
    for (int off = 32; off; off >>= 1) {
        a += __shfl_down(a, off, 64);
        b += __shfl_down(b, off, 64);
    }
    const int lane = threadIdx.x & 63;
    const int wid  = threadIdx.x >> 6;
    const int nw   = blockDim.x >> 6;
    if (lane == 0) lds[wid] = make_float2(a, b);
    __syncthreads();
    if (wid == 0) {
        float2 v = (lane < nw) ? lds[lane] : make_float2(0.f, 0.f);
        a = v.x; b = v.y;
        #pragma unroll
        for (int off = 8; off; off >>= 1) {
            a += __shfl_down(a, off, 64);
            b += __shfl_down(b, off, 64);
        }
        if (lane == 0) lds[0] = make_float2(a, b);
    }
    __syncthreads();
    float2 r = lds[0];
    __syncthreads();
    return r;
}

// ---------- fused kernel: hebb read ONCE, held in registers across LN ----------
__global__ __launch_bounds__(FT, 2) void fused_spin(
    const float* __restrict__ x, const float* __restrict__ hebb,
    const float* __restrict__ weight, const float* __restrict__ alpha,
    const float* __restrict__ ln_g, const float* __restrict__ ln_b,
    const float* __restrict__ mod_w, const float* __restrict__ mod_b,
    const float* __restrict__ fan_w, const float* __restrict__ fan_b,
    float* __restrict__ y_out, float* __restrict__ m_out,
    float* __restrict__ hebb_out,
    float* __restrict__ ws_part, int* __restrict__ cnt, int* __restrict__ flag)
{
    const int blk = (int)blockIdx.x;     // b*STRIPS + s  (strips consecutive!)
    const int b   = blk >> 4;
    const int s   = blk & (STRIPS - 1);
    const int tid = (int)threadIdx.x;
    const int o4  = tid & 127;
    const int rg  = tid >> 7;            // 0..3

    __shared__ float  xs[ROWS];
    __shared__ float4 part[4][OUT4];
    __shared__ float  y_lds[OUT_];
    __shared__ float2 rbuf[16];

    const int row0 = s * ROWS;
    if (tid < ROWS) {
        const int row = row0 + tid;
        xs[tid] = (row < IN_) ? x[(size_t)b * IN_ + row] : 1.0f;  // bias row = 1
    }
    __syncthreads();

    // ---- phase 1: stream strip into regs (NT), partial y_pre ----
    const fx4*    __restrict__ h4 = (const fx4*)hebb    + ((size_t)b * INP1 + row0 + rg) * OUT4 + o4;
    const float4* __restrict__ w4 = (const float4*)weight + (size_t)(row0 + rg) * OUT4 + o4;
    const float4* __restrict__ a4 = (const float4*)alpha  + (size_t)(row0 + rg) * OUT4 + o4;

    fx4 h[KPT];
    float4 acc = make_float4(0.f, 0.f, 0.f, 0.f);
    #pragma unroll
    for (int k = 0; k < KPT; ++k) {
        h[k] = __builtin_nontemporal_load(&h4[(size_t)k * (4 * OUT4)]);
        const float4 wv = w4[(size_t)k * (4 * OUT4)];
        const float4 av = a4[(size_t)k * (4 * OUT4)];
        const float  xv = xs[rg + 4 * k];
        acc.x = fmaf(xv, fmaf(av.x, h[k].x, wv.x), acc.x);
        acc.y = fmaf(xv, fmaf(av.y, h[k].y, wv.y), acc.y);
        acc.z = fmaf(xv, fmaf(av.z, h[k].z, wv.z), acc.z);
        acc.w = fmaf(xv, fmaf(av.w, h[k].w, wv.w), acc.w);
    }

    part[rg][o4] = acc;
    __syncthreads();
    if (rg == 0) {
        float4 p = part[0][o4];
        const float4 q1 = part[1][o4], q2 = part[2][o4], q3 = part[3][o4];
        p.x += q1.x + q2.x + q3.x;
        p.y += q1.y + q2.y + q3.y;
        p.z += q1.z + q2.z + q3.z;
        p.w += q1.w + q2.w + q3.w;
        ((float4*)ws_part)[((size_t)b * STRIPS + s) * OUT4 + o4] = p;
    }
    __syncthreads();                       // all partial stores issued
    if (tid == 0)
        __hip_atomic_fetch_add(&cnt[b], 1, __ATOMIC_RELEASE, __HIP_MEMORY_SCOPE_AGENT);

    float mval;
    if (s == 0) {
        // ---- strip 0: finish LN + modulator for sample b ----
        if (tid == 0) {
            while (__hip_atomic_load(&cnt[b], __ATOMIC_ACQUIRE, __HIP_MEMORY_SCOPE_AGENT) < STRIPS)
                __builtin_amdgcn_s_sleep(2);
        }
        __syncthreads();

        const int o = tid;
        float ypre = 0.f;
        #pragma unroll
        for (int t = 0; t < STRIPS; ++t)
            ypre += ws_part[((size_t)b * STRIPS + t) * OUT_ + o];

        float2 ss = block_reduce2(ypre, ypre * ypre, rbuf);
        const float mu   = ss.x * (1.0f / OUT_);
        const float var  = ss.y * (1.0f / OUT_) - mu * mu;
        const float rstd = rsqrtf(var + LNEPS);
        const float yv   = tanhf(fmaf(ln_g[o], (ypre - mu) * rstd, ln_b[o]));
        y_lds[o] = yv;
        y_out[(size_t)b * OUT_ + o] = yv;

        float2 ms = block_reduce2(yv * mod_w[o], 0.f, rbuf);
        mval = tanhf(ms.x + mod_b[0]);
        if (tid == 0) m_out[b] = mval;

        __syncthreads();                   // y_out/m_out stores drained
        if (tid == 0)
            __hip_atomic_store(&flag[b], 1, __ATOMIC_RELEASE, __HIP_MEMORY_SCOPE_AGENT);
    } else {
        // ---- siblings: wait for y/m, rebuild locally ----
        if (tid == 0) {
            while (__hip_atomic_load(&flag[b], __ATOMIC_ACQUIRE, __HIP_MEMORY_SCOPE_AGENT) == 0)
                __builtin_amdgcn_s_sleep(2);
        }
        __syncthreads();
        y_lds[tid] = y_out[(size_t)b * OUT_ + tid];
        mval = m_out[b];
        __syncthreads();
    }

    // ---- phase 2: update register-held strip, NT-stream out ----
    const float4 yv4 = ((const float4*)y_lds)[o4];
    const float4 fw  = ((const float4*)fan_w)[o4];
    const float4 fb  = ((const float4*)fan_b)[o4];
    fx4 coef;
    coef.x = fmaf(mval, fw.x, fb.x) * yv4.x;
    coef.y = fmaf(mval, fw.y, fb.y) * yv4.y;
    coef.z = fmaf(mval, fw.z, fb.z) * yv4.z;
    coef.w = fmaf(mval, fw.w, fb.w) * yv4.w;

    fx4* __restrict__ ho4 = (fx4*)hebb_out + ((size_t)b * INP1 + row0 + rg) * OUT4 + o4;
    #pragma unroll
    for (int k = 0; k < KPT; ++k) {
        const float xv = xs[rg + 4 * k];
        fx4 rr;
        rr.x = fminf(fmaxf(fmaf(coef.x, xv, h[k].x), -CLIPV), CLIPV);
        rr.y = fminf(fmaxf(fmaf(coef.y, xv, h[k].y), -CLIPV), CLIPV);
        rr.z = fminf(fmaxf(fmaf(coef.z, xv, h[k].z), -CLIPV), CLIPV);
        rr.w = fminf(fmaxf(fmaf(coef.w, xv, h[k].w), -CLIPV), CLIPV);
        __builtin_nontemporal_store(rr, &ho4[(size_t)k * (4 * OUT4)]);
    }
}

// ---------------- fallback path (proven R3 structure, 649 us) ----------------
#define SLABS    4
#define SLABROWS 256
#define NBS      (B_ * SLABS)

__global__ __launch_bounds__(256) void k1a_partial(
    const float* __restrict__ x, const float* __restrict__ hebb,
    const float* __restrict__ weight, const float* __restrict__ alpha,
    float* __restrict__ ws_part)
{
    const int bs   = (int)blockIdx.x;
    const int b    = bs >> 2;
    const int s    = bs & 3;
    const int tid  = (int)threadIdx.x;
    const int o4   = tid & 127;
    const int half = tid >> 7;

    __shared__ float  xs[SLABROWS];
    __shared__ float4 part[2][OUT4];

    {
        const int i = s * SLABROWS + tid;
        xs[tid] = (i < IN_) ? x[(size_t)b * IN_ + i] : 1.0f;
    }
    __syncthreads();

    const int i0 = s * SLABROWS + half * 128;
    const float4* __restrict__ h4 = (const float4*)hebb  + ((size_t)b * INP1 + i0) * OUT4 + o4;
    const float4* __restrict__ w4 = (const float4*)weight + (size_t)i0 * OUT4 + o4;
    const float4* __restrict__ a4 = (const float4*)alpha  + (size_t)i0 * OUT4 + o4;
    const float* __restrict__ xk = xs + half * 128;

    float4 acc = make_float4(0.f, 0.f, 0.f, 0.f);
    #pragma unroll 4
    for (int k = 0; k < 128; ++k) {
        const float  xv = xk[k];
        const float4 h  = h4[(size_t)k * OUT4];
        const float4 w  = w4[(size_t)k * OUT4];
        const float4 a  = a4[(size_t)k * OUT4];
        acc.x = fmaf(xv, fmaf(a.x, h.x, w.x), acc.x);
        acc.y = fmaf(xv, fmaf(a.y, h.y, w.y), acc.y);
        acc.z = fmaf(xv, fmaf(a.z, h.z, w.z), acc.z);
        acc.w = fmaf(xv, fmaf(a.w, h.w, w.w), acc.w);
    }

    part[half][o4] = acc;
    __syncthreads();
    if (half == 0) {
        float4 p = part[0][o4];
        const float4 q = part[1][o4];
        p.x += q.x; p.y += q.y; p.z += q.z; p.w += q.w;
        ((float4*)ws_part)[(size_t)bs * OUT4 + o4] = p;
    }
}

__global__ __launch_bounds__(512) void k1b_ln_mod(
    const float* __restrict__ ws_part,
    const float* __restrict__ ln_g, const float* __restrict__ ln_b,
    const float* __restrict__ mod_w, const float* __restrict__ mod_b,
    float* __restrict__ y_out, float* __restrict__ m_out)
{
    const int b = (int)blockIdx.x;
    const int o = (int)threadIdx.x;
    __shared__ float2 rbuf[16];

    float ypre = 0.f;
    #pragma unroll
    for (int s = 0; s < SLABS; ++s)
        ypre += ws_part[((size_t)b * SLABS + s) * OUT_ + o];

    float2 ss = block_reduce2(ypre, ypre * ypre, rbuf);
    const float mu   = ss.x * (1.0f / OUT_);
    const float var  = ss.y * (1.0f / OUT_) - mu * mu;
    const float rstd = rsqrtf(var + LNEPS);

    const float yv = tanhf(fmaf(ln_g[o], (ypre - mu) * rstd, ln_b[o]));
    y_out[(size_t)b * OUT_ + o] = yv;

    float2 ms = block_reduce2(yv * mod_w[o], 0.f, rbuf);
    if (o == 0) m_out[b] = tanhf(ms.x + mod_b[0]);
}

__global__ __launch_bounds__(256) void k2_update(
    const float* __restrict__ x, const float* __restrict__ hebb,
    const float* __restrict__ y, const float* __restrict__ m,
    const float* __restrict__ fan_w, const float* __restrict__ fan_b,
    float* __restrict__ hebb_out)
{
    const int bsr  = NBS - 1 - (int)blockIdx.x;
    const int b    = bsr >> 2;
    const int s    = bsr & 3;
    const int tid  = (int)threadIdx.x;
    const int o4   = tid & 127;
    const int half = tid >> 7;

    __shared__ float xs[SLABROWS];
    {
        const int i = s * SLABROWS + tid;
        xs[tid] = (i < IN_) ? x[(size_t)b * IN_ + i] : 1.0f;
    }
    __syncthreads();

    const float  mb = m[b];
    const float4 yv = ((const float4*)y)[(size_t)b * OUT4 + o4];
    const float4 fw = ((const float4*)fan_w)[o4];
    const float4 fb = ((const float4*)fan_b)[o4];
    float4 coef;
    coef.x = fmaf(mb, fw.x, fb.x) * yv.x;
    coef.y = fmaf(mb, fw.y, fb.y) * yv.y;
    coef.z = fmaf(mb, fw.z, fb.z) * yv.z;
    coef.w = fmaf(mb, fw.w, fb.w) * yv.w;

    const int i0 = s * SLABROWS + half * 128;
    const size_t base = ((size_t)b * INP1 + i0) * OUT4 + o4;
    const fx4* __restrict__ h4  = (const fx4*)hebb + base;
    fx4* __restrict__       ho4 = (fx4*)hebb_out + base;
    const float* __restrict__ xk = xs + half * 128;

    #pragma unroll 4
    for (int k = 0; k < 128; ++k) {
        const float xv = xk[k];
        const fx4   h  = h4[(size_t)k * OUT4];
        fx4 r;
        r.x = fminf(fmaxf(fmaf(coef.x, xv, h.x), -CLIPV), CLIPV);
        r.y = fminf(fmaxf(fmaf(coef.y, xv, h.y), -CLIPV), CLIPV);
        r.z = fminf(fmaxf(fmaf(coef.z, xv, h.z), -CLIPV), CLIPV);
        r.w = fminf(fmaxf(fmaf(coef.w, xv, h.w), -CLIPV), CLIPV);
        __builtin_nontemporal_store(r, &ho4[(size_t)k * OUT4]);
    }
}

extern "C" void kernel_launch(void* const* d_in, const int* in_sizes, int n_in,
                              void* d_out, int out_size, void* d_ws, size_t ws_size,
                              hipStream_t stream) {
    const float* x      = (const float*)d_in[0];
    const float* hebb   = (const float*)d_in[1];
    const float* weight = (const float*)d_in[2];
    const float* alpha  = (const float*)d_in[3];
    const float* ln_g   = (const float*)d_in[4];
    const float* ln_b   = (const float*)d_in[5];
    const float* mod_w  = (const float*)d_in[6];
    const float* mod_b  = (const float*)d_in[7];
    const float* fan_w  = (const float*)d_in[8];
    const float* fan_b  = (const float*)d_in[9];

    float* out      = (float*)d_out;
    float* y_out    = out;                               // [B, OUT]
    float* m_out    = out + (size_t)B_ * OUT_;           // [B]
    float* hebb_out = m_out + B_;                        // [B, IN+1, OUT]

    const size_t part_floats = (size_t)B_ * STRIPS * OUT_;        // 16 MiB
    const size_t need = part_floats * sizeof(float) + 2 * B_ * sizeof(int);

    if (ws_size >= need) {
        float* ws_part = (float*)d_ws;
        int*   cnt     = (int*)((char*)d_ws + part_floats * sizeof(float));
        int*   flag    = cnt + B_;
        hipMemsetAsync(cnt, 0, 2 * B_ * sizeof(int), stream);
        fused_spin<<<B_ * STRIPS, FT, 0, stream>>>(
            x, hebb, weight, alpha, ln_g, ln_b, mod_w, mod_b, fan_w, fan_b,
            y_out, m_out, hebb_out, ws_part, cnt, flag);
    } else {
        const size_t part_bytes = (size_t)B_ * SLABS * OUT_ * sizeof(float);
        float* ws_part = (ws_size >= part_bytes) ? (float*)d_ws : hebb_out;
        k1a_partial<<<NBS, 256, 0, stream>>>(x, hebb, weight, alpha, ws_part);
        k1b_ln_mod<<<B_, OUT_, 0, stream>>>(ws_part, ln_g, ln_b, mod_w, mod_b,
                                            y_out, m_out);
        k2_update<<<NBS, 256, 0, stream>>>(x, hebb, y_out, m_out,
                                           fan_w, fan_b, hebb_out);
    }
}

// Round 8
// 703.340 us; speedup vs baseline: 1.8667x; 1.8667x over previous
//
#include <hip/hip_runtime.h>
#include <cstddef>

#define B_     512
#define IN_    1023
#define INP1   1024
#define OUT_   512
#define OUT4   128
#define CLIPV  2.0f
#define LNEPS  1e-5f

// k1a grouped geometry
#define G_      16            // samples per group (W/alpha amortization factor)
#define NGRP    32            // B_/G_
#define RSTRIP  64            // rows per k1a block
#define NSID    16            // INP1/RSTRIP strips per sample

// k2 geometry (R3 proven)
#define K2S     4
#define K2ROWS  256
#define NBS2    (B_ * K2S)

typedef float fx4 __attribute__((ext_vector_type(4)));

__device__ __forceinline__ float2 block_reduce2(float a, float b, float2* lds) {
    #pragma unroll
    for (int off = 32; off; off >>= 1) {
        a += __shfl_down(a, off, 64);
        b += __shfl_down(b, off, 64);
    }
    const int lane = threadIdx.x & 63;
    const int wid  = threadIdx.x >> 6;
    const int nw   = blockDim.x >> 6;
    if (lane == 0) lds[wid] = make_float2(a, b);
    __syncthreads();
    if (wid == 0) {
        float2 v = (lane < nw) ? lds[lane] : make_float2(0.f, 0.f);
        a = v.x; b = v.y;
        #pragma unroll
        for (int off = 8; off; off >>= 1) {
            a += __shfl_down(a, off, 64);
            b += __shfl_down(b, off, 64);
        }
        if (lane == 0) lds[0] = make_float2(a, b);
    }
    __syncthreads();
    float2 r = lds[0];
    __syncthreads();
    return r;
}

// k1a: block = (16-sample group, 64-row strip). W/alpha rows loaded ONCE per
// block and reused for 16 samples -> W/alpha L3 traffic drops 4.3 GB -> 0.13 GB.
// 512 blocks x 512 thr (2/CU), acc[16] fx4 = 64 VGPR.
__global__ __launch_bounds__(512, 4) void k1a_grouped(
    const float* __restrict__ x, const float* __restrict__ hebb,
    const float* __restrict__ weight, const float* __restrict__ alpha,
    float* __restrict__ ws_part)
{
    const int blk = (int)blockIdx.x;   // gid*NSID + sid
    const int gid = blk >> 4;
    const int sid = blk & (NSID - 1);
    const int b0  = gid * G_;
    const int r0  = sid * RSTRIP;
    const int tid = (int)threadIdx.x;
    const int o4  = tid & 127;
    const int rg  = tid >> 7;          // 0..3 row sub-groups (16 rows each)

    __shared__ float  xs[G_][RSTRIP];  // 4 KB
    __shared__ float4 pl[4][OUT4];     // 8 KB

    {   // stage x for all 16 samples: thread -> (g, j), loads j and j+32
        const int g = tid >> 5, j = tid & 31;
        const int ra = r0 + j, rb = r0 + j + 32;
        xs[g][j]      = (ra < IN_) ? x[(size_t)(b0 + g) * IN_ + ra] : 1.0f;
        xs[g][j + 32] = (rb < IN_) ? x[(size_t)(b0 + g) * IN_ + rb] : 1.0f;
    }
    __syncthreads();

    fx4 acc[G_];
    #pragma unroll
    for (int g = 0; g < G_; ++g) acc[g] = (fx4){0.f, 0.f, 0.f, 0.f};

    // rows handled by this rg: r0 + rg*16 + il, il = 0..15 (contiguous runs)
    for (int il = 0; il < 16; ++il) {
        const int rr  = rg * 16 + il;          // row offset in strip
        const int row = r0 + rr;
        const float4 wv = ((const float4*)weight)[(size_t)row * OUT4 + o4];
        const float4 av = ((const float4*)alpha )[(size_t)row * OUT4 + o4];
        #pragma unroll
        for (int g = 0; g < G_; ++g) {
            const fx4 h = ((const fx4*)hebb)[((size_t)(b0 + g) * INP1 + row) * OUT4 + o4];
            const float xv = xs[g][rr];
            acc[g].x = fmaf(xv, fmaf(av.x, h.x, wv.x), acc[g].x);
            acc[g].y = fmaf(xv, fmaf(av.y, h.y, wv.y), acc[g].y);
            acc[g].z = fmaf(xv, fmaf(av.z, h.z, wv.z), acc[g].z);
            acc[g].w = fmaf(xv, fmaf(av.w, h.w, wv.w), acc[g].w);
        }
    }

    // reduce the 4 rg partials per sample in LDS, write one partial per (b,sid)
    for (int g = 0; g < G_; ++g) {
        pl[rg][o4] = make_float4(acc[g].x, acc[g].y, acc[g].z, acc[g].w);
        __syncthreads();
        if (rg == 0) {
            float4 p = pl[0][o4];
            const float4 q1 = pl[1][o4], q2 = pl[2][o4], q3 = pl[3][o4];
            p.x += q1.x + q2.x + q3.x;
            p.y += q1.y + q2.y + q3.y;
            p.z += q1.z + q2.z + q3.z;
            p.w += q1.w + q2.w + q3.w;
            ((float4*)ws_part)[((size_t)(b0 + g) * NSID + sid) * OUT4 + o4] = p;
        }
        __syncthreads();
    }
}

// k1b: sum 16 strip partials -> LayerNorm -> tanh -> y, m. 512 blocks x 512 thr.
__global__ __launch_bounds__(512) void k1b_ln_mod(
    const float* __restrict__ ws_part,
    const float* __restrict__ ln_g, const float* __restrict__ ln_b,
    const float* __restrict__ mod_w, const float* __restrict__ mod_b,
    float* __restrict__ y_out, float* __restrict__ m_out)
{
    const int b = (int)blockIdx.x;
    const int o = (int)threadIdx.x;
    __shared__ float2 rbuf[16];

    float ypre = 0.f;
    #pragma unroll
    for (int s = 0; s < NSID; ++s)
        ypre += ws_part[((size_t)b * NSID + s) * OUT_ + o];

    float2 ss = block_reduce2(ypre, ypre * ypre, rbuf);
    const float mu   = ss.x * (1.0f / OUT_);
    const float var  = ss.y * (1.0f / OUT_) - mu * mu;
    const float rstd = rsqrtf(var + LNEPS);

    const float yv = tanhf(fmaf(ln_g[o], (ypre - mu) * rstd, ln_b[o]));
    y_out[(size_t)b * OUT_ + o] = yv;

    float2 ms = block_reduce2(yv * mod_w[o], 0.f, rbuf);
    if (o == 0) m_out[b] = tanhf(ms.x + mod_b[0]);
}

// k2: hebb_new = clip(hebb + coef_o * x_i, +-CLIP)  (R3 proven form)
__global__ __launch_bounds__(256) void k2_update(
    const float* __restrict__ x, const float* __restrict__ hebb,
    const float* __restrict__ y, const float* __restrict__ m,
    const float* __restrict__ fan_w, const float* __restrict__ fan_b,
    float* __restrict__ hebb_out)
{
    const int bsr  = NBS2 - 1 - (int)blockIdx.x;   // reverse order (L3 tail)
    const int b    = bsr >> 2;
    const int s    = bsr & 3;
    const int tid  = (int)threadIdx.x;
    const int o4   = tid & 127;
    const int half = tid >> 7;

    __shared__ float xs[K2ROWS];
    {
        const int i = s * K2ROWS + tid;
        xs[tid] = (i < IN_) ? x[(size_t)b * IN_ + i] : 1.0f;
    }
    __syncthreads();

    const float  mb = m[b];
    const float4 yv = ((const float4*)y)[(size_t)b * OUT4 + o4];
    const float4 fw = ((const float4*)fan_w)[o4];
    const float4 fb = ((const float4*)fan_b)[o4];
    float4 coef;
    coef.x = fmaf(mb, fw.x, fb.x) * yv.x;
    coef.y = fmaf(mb, fw.y, fb.y) * yv.y;
    coef.z = fmaf(mb, fw.z, fb.z) * yv.z;
    coef.w = fmaf(mb, fw.w, fb.w) * yv.w;

    const int i0 = s * K2ROWS + half * 128;
    const size_t base = ((size_t)b * INP1 + i0) * OUT4 + o4;
    const fx4* __restrict__ h4  = (const fx4*)hebb + base;
    fx4* __restrict__       ho4 = (fx4*)hebb_out + base;
    const float* __restrict__ xk = xs + half * 128;

    #pragma unroll 4
    for (int k = 0; k < 128; ++k) {
        const float xv = xk[k];
        const fx4   h  = h4[(size_t)k * OUT4];
        fx4 r;
        r.x = fminf(fmaxf(fmaf(coef.x, xv, h.x), -CLIPV), CLIPV);
        r.y = fminf(fmaxf(fmaf(coef.y, xv, h.y), -CLIPV), CLIPV);
        r.z = fminf(fmaxf(fmaf(coef.z, xv, h.z), -CLIPV), CLIPV);
        r.w = fminf(fmaxf(fmaf(coef.w, xv, h.w), -CLIPV), CLIPV);
        __builtin_nontemporal_store(r, &ho4[(size_t)k * OUT4]);
    }
}

extern "C" void kernel_launch(void* const* d_in, const int* in_sizes, int n_in,
                              void* d_out, int out_size, void* d_ws, size_t ws_size,
                              hipStream_t stream) {
    const float* x      = (const float*)d_in[0];
    const float* hebb   = (const float*)d_in[1];
    const float* weight = (const float*)d_in[2];
    const float* alpha  = (const float*)d_in[3];
    const float* ln_g   = (const float*)d_in[4];
    const float* ln_b   = (const float*)d_in[5];
    const float* mod_w  = (const float*)d_in[6];
    const float* mod_b  = (const float*)d_in[7];
    const float* fan_w  = (const float*)d_in[8];
    const float* fan_b  = (const float*)d_in[9];

    float* out      = (float*)d_out;
    float* y_out    = out;                               // [B, OUT]
    float* m_out    = out + (size_t)B_ * OUT_;           // [B]
    float* hebb_out = m_out + B_;                        // [B, IN+1, OUT]

    // partials: B * NSID * OUT floats = 16 MiB
    const size_t part_bytes = (size_t)B_ * NSID * OUT_ * sizeof(float);
    float* ws_part = (ws_size >= part_bytes)
                   ? (float*)d_ws
                   : hebb_out;   // safe: fully consumed by k1b before k2 writes

    k1a_grouped<<<NGRP * NSID, 512, 0, stream>>>(x, hebb, weight, alpha, ws_part);
    k1b_ln_mod<<<B_, OUT_, 0, stream>>>(ws_part, ln_g, ln_b, mod_w, mod_b,
                                        y_out, m_out);
    k2_update<<<NBS2, 256, 0, stream>>>(x, hebb, y_out, m_out,
                                        fan_w, fan_b, hebb_out);
}

// Round 9
// 590.933 us; speedup vs baseline: 2.2218x; 1.1902x over previous
//
#include <hip/hip_runtime.h>
#include <cstddef>

#define B_     512
#define IN_    1023
#define INP1   1024
#define OUT_   512
#define OUT4   128
#define CLIPV  2.0f
#define LNEPS  1e-5f

// k1a grouped geometry: 4 samples/block, 128-row slabs
#define G_      4
#define NGRP    128          // B_/G_
#define NSLAB   8            // INP1/128
#define SLROWS  128

// k2 geometry (R3 proven)
#define K2S     4
#define K2ROWS  256
#define NBS2    (B_ * K2S)

typedef float fx4 __attribute__((ext_vector_type(4)));

__device__ __forceinline__ float2 block_reduce2(float a, float b, float2* lds) {
    #pragma unroll
    for (int off = 32; off; off >>= 1) {
        a += __shfl_down(a, off, 64);
        b += __shfl_down(b, off, 64);
    }
    const int lane = threadIdx.x & 63;
    const int wid  = threadIdx.x >> 6;
    const int nw   = blockDim.x >> 6;
    if (lane == 0) lds[wid] = make_float2(a, b);
    __syncthreads();
    if (wid == 0) {
        float2 v = (lane < nw) ? lds[lane] : make_float2(0.f, 0.f);
        a = v.x; b = v.y;
        #pragma unroll
        for (int off = 8; off; off >>= 1) {
            a += __shfl_down(a, off, 64);
            b += __shfl_down(b, off, 6 + 2);  // placeholder fixed below
        }
        if (lane == 0) lds[0] = make_float2(a, b);
    }
    __syncthreads();
    float2 r = lds[0];
    __syncthreads();
    return r;
}

// NOTE: the shuffle width arg above must be 64; re-define cleanly:
__device__ __forceinline__ float2 block_reduce2_fix(float a, float b, float2* lds) {
    #pragma unroll
    for (int off = 32; off; off >>= 1) {
        a += __shfl_down(a, off, 64);
        b += __shfl_down(b, off, 64);
    }
    const int lane = threadIdx.x & 63;
    const int wid  = threadIdx.x >> 6;
    const int nw   = blockDim.x >> 6;
    if (lane == 0) lds[wid] = make_float2(a, b);
    __syncthreads();
    if (wid == 0) {
        float2 v = (lane < nw) ? lds[lane] : make_float2(0.f, 0.f);
        a = v.x; b = v.y;
        #pragma unroll
        for (int off = 8; off; off >>= 1) {
            a += __shfl_down(a, off, 64);
            b += __shfl_down(b, off, 64);
        }
        if (lane == 0) lds[0] = make_float2(a, b);
    }
    __syncthreads();
    float2 r = lds[0];
    __syncthreads();
    return r;
}

// k1a: block = (4-sample group, 128-row slab). W/alpha loaded once, reused
// across 4 samples -> W/alpha cache demand 2 GB -> 0.5 GB; hebb stays as 4
// linear streams. 1024 blocks x 256 thr.
__global__ __launch_bounds__(256) void k1a_g4(
    const float* __restrict__ x, const float* __restrict__ hebb,
    const float* __restrict__ weight, const float* __restrict__ alpha,
    float* __restrict__ ws_part)
{
    const int blk  = (int)blockIdx.x;      // gid*NSLAB + slab (slab fastest -> XCD-fixed slab)
    const int gid  = blk >> 3;
    const int slab = blk & (NSLAB - 1);
    const int b0   = gid * G_;
    const int tid  = (int)threadIdx.x;
    const int o4   = tid & 127;
    const int half = tid >> 7;             // 0..1

    __shared__ float  xs[G_][SLROWS];
    __shared__ float4 pl[2][OUT4];

    {   // stage x for the 4 samples' 128 rows (512 values, 2 per thread)
        #pragma unroll
        for (int u = 0; u < 2; ++u) {
            const int idx = tid * 2 + u;
            const int g = idx >> 7, j = idx & 127;
            const int row = slab * SLROWS + j;
            xs[g][j] = (row < IN_) ? x[(size_t)(b0 + g) * IN_ + row] : 1.0f;
        }
    }
    __syncthreads();

    const int r0 = slab * SLROWS + half * 64;
    const float4* __restrict__ w4 = (const float4*)weight + (size_t)r0 * OUT4 + o4;
    const float4* __restrict__ a4 = (const float4*)alpha  + (size_t)r0 * OUT4 + o4;

    fx4 acc[G_];
    #pragma unroll
    for (int g = 0; g < G_; ++g) acc[g] = (fx4){0.f, 0.f, 0.f, 0.f};

    #pragma unroll 4
    for (int k = 0; k < 64; ++k) {
        const int j = half * 64 + k;
        const float4 wv = w4[(size_t)k * OUT4];
        const float4 av = a4[(size_t)k * OUT4];
        #pragma unroll
        for (int g = 0; g < G_; ++g) {
            const fx4 h = ((const fx4*)hebb)[((size_t)(b0 + g) * INP1 + r0 + k) * OUT4 + o4];
            const float xv = xs[g][j];
            acc[g].x = fmaf(xv, fmaf(av.x, h.x, wv.x), acc[g].x);
            acc[g].y = fmaf(xv, fmaf(av.y, h.y, wv.y), acc[g].y);
            acc[g].z = fmaf(xv, fmaf(av.z, h.z, wv.z), acc[g].z);
            acc[g].w = fmaf(xv, fmaf(av.w, h.w, wv.w), acc[g].w);
        }
    }

    // combine halves per sample and emit one partial per (b, slab)
    #pragma unroll
    for (int g = 0; g < G_; ++g) {
        pl[half][o4] = make_float4(acc[g].x, acc[g].y, acc[g].z, acc[g].w);
        __syncthreads();
        if (half == 0) {
            float4 p = pl[0][o4];
            const float4 q = pl[1][o4];
            p.x += q.x; p.y += q.y; p.z += q.z; p.w += q.w;
            ((float4*)ws_part)[((size_t)(b0 + g) * NSLAB + slab) * OUT4 + o4] = p;
        }
        __syncthreads();
    }
}

// k1b: sum 8 slab partials -> LayerNorm -> tanh -> y, m. 512 blocks x 512 thr.
__global__ __launch_bounds__(512) void k1b_ln_mod(
    const float* __restrict__ ws_part,
    const float* __restrict__ ln_g, const float* __restrict__ ln_b,
    const float* __restrict__ mod_w, const float* __restrict__ mod_b,
    float* __restrict__ y_out, float* __restrict__ m_out)
{
    const int b = (int)blockIdx.x;
    const int o = (int)threadIdx.x;
    __shared__ float2 rbuf[16];

    float ypre = 0.f;
    #pragma unroll
    for (int s = 0; s < NSLAB; ++s)
        ypre += ws_part[((size_t)b * NSLAB + s) * OUT_ + o];

    float2 ss = block_reduce2_fix(ypre, ypre * ypre, rbuf);
    const float mu   = ss.x * (1.0f / OUT_);
    const float var  = ss.y * (1.0f / OUT_) - mu * mu;
    const float rstd = rsqrtf(var + LNEPS);

    const float yv = tanhf(fmaf(ln_g[o], (ypre - mu) * rstd, ln_b[o]));
    y_out[(size_t)b * OUT_ + o] = yv;

    float2 ms = block_reduce2_fix(yv * mod_w[o], 0.f, rbuf);
    if (o == 0) m_out[b] = tanhf(ms.x + mod_b[0]);
}

// k2: hebb_new = clip(hebb + coef_o * x_i, +-CLIP)  (R3 proven form, unchanged)
__global__ __launch_bounds__(256) void k2_update(
    const float* __restrict__ x, const float* __restrict__ hebb,
    const float* __restrict__ y, const float* __restrict__ m,
    const float* __restrict__ fan_w, const float* __restrict__ fan_b,
    float* __restrict__ hebb_out)
{
    const int bsr  = NBS2 - 1 - (int)blockIdx.x;   // reverse order (L3 tail)
    const int b    = bsr >> 2;
    const int s    = bsr & 3;
    const int tid  = (int)threadIdx.x;
    const int o4   = tid & 127;
    const int half = tid >> 7;

    __shared__ float xs[K2ROWS];
    {
        const int i = s * K2ROWS + tid;
        xs[tid] = (i < IN_) ? x[(size_t)b * IN_ + i] : 1.0f;
    }
    __syncthreads();

    const float  mb = m[b];
    const float4 yv = ((const float4*)y)[(size_t)b * OUT4 + o4];
    const float4 fw = ((const float4*)fan_w)[o4];
    const float4 fb = ((const float4*)fan_b)[o4];
    float4 coef;
    coef.x = fmaf(mb, fw.x, fb.x) * yv.x;
    coef.y = fmaf(mb, fw.y, fb.y) * yv.y;
    coef.z = fmaf(mb, fw.z, fb.z) * yv.z;
    coef.w = fmaf(mb, fw.w, fb.w) * yv.w;

    const int i0 = s * K2ROWS + half * 128;
    const size_t base = ((size_t)b * INP1 + i0) * OUT4 + o4;
    const fx4* __restrict__ h4  = (const fx4*)hebb + base;
    fx4* __restrict__       ho4 = (fx4*)hebb_out + base;
    const float* __restrict__ xk = xs + half * 128;

    #pragma unroll 4
    for (int k = 0; k < 128; ++k) {
        const float xv = xk[k];
        const fx4   h  = h4[(size_t)k * OUT4];
        fx4 r;
        r.x = fminf(fmaxf(fmaf(coef.x, xv, h.x), -CLIPV), CLIPV);
        r.y = fminf(fmaxf(fmaf(coef.y, xv, h.y), -CLIPV), CLIPV);
        r.z = fminf(fmaxf(fmaf(coef.z, xv, h.z), -CLIPV), CLIPV);
        r.w = fminf(fmaxf(fmaf(coef.w, xv, h.w), -CLIPV), CLIPV);
        __builtin_nontemporal_store(r, &ho4[(size_t)k * OUT4]);
    }
}

extern "C" void kernel_launch(void* const* d_in, const int* in_sizes, int n_in,
                              void* d_out, int out_size, void* d_ws, size_t ws_size,
                              hipStream_t stream) {
    const float* x      = (const float*)d_in[0];
    const float* hebb   = (const float*)d_in[1];
    const float* weight = (const float*)d_in[2];
    const float* alpha  = (const float*)d_in[3];
    const float* ln_g   = (const float*)d_in[4];
    const float* ln_b   = (const float*)d_in[5];
    const float* mod_w  = (const float*)d_in[6];
    const float* mod_b  = (const float*)d_in[7];
    const float* fan_w  = (const float*)d_in[8];
    const float* fan_b  = (const float*)d_in[9];

    float* out      = (float*)d_out;
    float* y_out    = out;                               // [B, OUT]
    float* m_out    = out + (size_t)B_ * OUT_;           // [B]
    float* hebb_out = m_out + B_;                        // [B, IN+1, OUT]

    // partials: B * NSLAB * OUT floats = 8 MiB (ws proven >= 16 MiB in R5/R7)
    const size_t part_bytes = (size_t)B_ * NSLAB * OUT_ * sizeof(float);
    float* ws_part = (ws_size >= part_bytes)
                   ? (float*)d_ws
                   : hebb_out;   // safe: fully consumed by k1b before k2 writes

    k1a_g4<<<NGRP * NSLAB, 256, 0, stream>>>(x, hebb, weight, alpha, ws_part);
    k1b_ln_mod<<<B_, OUT_, 0, stream>>>(ws_part, ln_g, ln_b, mod_w, mod_b,
                                        y_out, m_out);
    k2_update<<<NBS2, 256, 0, stream>>>(x, hebb, y_out, m_out,
                                        fan_w, fan_b, hebb_out);
}